// Round 4
// baseline (2124.764 us; speedup 1.0000x reference)
//
#include <hip/hip_runtime.h>

#define DPDIM 32         // path/link state dim
#define GCOLS 96         // 3*DPDIM gate columns
#define PLEN 8
#define T_ITERS 8
#define RUNITS 256

// ---------------- fast activations (v_exp_f32 + v_rcp_f32) ----------------
__device__ __forceinline__ float fast_sigmoid(float a) {
    return __builtin_amdgcn_rcpf(1.0f + __expf(-a));
}
__device__ __forceinline__ float fast_tanh(float a) {
    return 1.0f - 2.0f * __builtin_amdgcn_rcpf(1.0f + __expf(2.0f * a));
}

#define ACC4F(A, s, V) \
    A.x = fmaf((s), (V).x, A.x); A.y = fmaf((s), (V).y, A.y); \
    A.z = fmaf((s), (V).z, A.z); A.w = fmaf((s), (V).w, A.w);

// ---------------- init states ----------------
__global__ __launch_bounds__(256) void init_kernel(
    const float* __restrict__ traffic, const float* __restrict__ packets,
    const float* __restrict__ eqlam, const float* __restrict__ avgpkt,
    const float* __restrict__ capacity, const float* __restrict__ queues,
    float* __restrict__ path_state, float* __restrict__ link_state,
    int n_paths, int n_links)
{
    int i = blockIdx.x * 256 + threadIdx.x;
    if (i < n_paths) {
        float4* row = (float4*)(path_state + (size_t)i * DPDIM);
        row[0] = make_float4(traffic[i], packets[i], eqlam[i], avgpkt[i]);
        float4 z = make_float4(0.f, 0.f, 0.f, 0.f);
        #pragma unroll
        for (int k = 1; k < 8; ++k) row[k] = z;
    }
    if (i < n_links) {
        float4* row = (float4*)(link_state + (size_t)i * DPDIM);
        row[0] = make_float4(capacity[i], queues[i], 0.f, 0.f);
        float4 z = make_float4(0.f, 0.f, 0.f, 0.f);
        #pragma unroll
        for (int k = 1; k < 8; ++k) row[k] = z;
    }
}

// ---------------- weight transpose: W[k][96] -> WT[jb][k][12] --------------
// WT[((jb*32)+k)*12 + idx], idx 0..3 = z cols jb*4+c, 4..7 = r, 8..11 = h
__global__ __launch_bounds__(256) void transpose_w_kernel(
    const float* __restrict__ W, float* __restrict__ WT)
{
    int i = blockIdx.x * 256 + threadIdx.x;
    if (i >= 8*32*12) return;
    int idx = i % 12;
    int k   = (i / 12) % 32;
    int jb  = i / (12*32);
    int gate = idx >> 2, c = idx & 3;
    WT[i] = W[k*GCOLS + gate*32 + jb*4 + c];
}

// ---------------- CSR build ----------------
__global__ __launch_bounds__(256) void zero_counts_kernel(int* __restrict__ counts, int n) {
    int i = blockIdx.x * 256 + threadIdx.x;
    if (i < n) counts[i] = 0;
}
__global__ __launch_bounds__(256) void hist_kernel(
    const int* __restrict__ link_to_path, int* __restrict__ counts, int n) {
    int i = blockIdx.x * 256 + threadIdx.x;
    if (i < n) atomicAdd(&counts[link_to_path[i]], 1);
}
__global__ __launch_bounds__(1024) void scan_kernel(
    const int* __restrict__ counts, int* __restrict__ offsets,
    int* __restrict__ cursor, int n)
{
    __shared__ int s[1024];
    int t = threadIdx.x;
    int chunk = (n + 1023) >> 10;
    int lo = t * chunk;
    int hi = lo + chunk; if (hi > n) hi = n;
    int local = 0;
    for (int i = lo; i < hi; ++i) local += counts[i];
    s[t] = local;
    __syncthreads();
    for (int d = 1; d < 1024; d <<= 1) {
        int v = (t >= d) ? s[t - d] : 0;
        __syncthreads();
        s[t] += v;
        __syncthreads();
    }
    int base = (t > 0) ? s[t - 1] : 0;
    for (int i = lo; i < hi; ++i) {
        offsets[i] = base; cursor[i] = base; base += counts[i];
    }
    if (t == 1023) offsets[n] = s[1023];
}
__global__ __launch_bounds__(256) void fill_kernel(
    const int* __restrict__ link_to_path, int* __restrict__ cursor,
    int* __restrict__ entries, int n) {
    int e = blockIdx.x * 256 + threadIdx.x;
    if (e < n) {
        int l = link_to_path[e];
        int pos = atomicAdd(&cursor[l], 1);
        entries[pos] = e >> 3;   // path id (PLEN == 8)
    }
}

// ---------------- gate precompute: G = X@W + bi (+bh for z,r) --------------
// G_z = x@Wz + biz + bhz ; G_r = x@Wr + bir + bhr ; G_h = x@Wh + bih
// x in registers (static), weights via wave-uniform scalar loads (WT layout),
// accumulate-from-zero so the stores are the only memory dependency.
__global__ __launch_bounds__(64) void gate_pre_kernel(
    const float* __restrict__ X, const float* __restrict__ WT,
    const float* __restrict__ bi, const float* __restrict__ bh,
    float* __restrict__ G, int* __restrict__ nzf, int n)
{
    int i = blockIdx.x * 64 + threadIdx.x;
    if (i >= n) return;
    float x[DPDIM];
    bool nz = false;
    const float4* row = (const float4*)(X + (size_t)i * DPDIM);
    #pragma unroll
    for (int k4 = 0; k4 < 8; ++k4) {
        float4 v = row[k4];
        x[4*k4+0]=v.x; x[4*k4+1]=v.y; x[4*k4+2]=v.z; x[4*k4+3]=v.w;
        nz = nz || (v.x != 0.f) || (v.y != 0.f) || (v.z != 0.f) || (v.w != 0.f);
    }
    float* Gp = G + (size_t)i * GCOLS;
    #pragma unroll 1
    for (int jb = 0; jb < 8; ++jb) {
        float4 az = {0.f,0.f,0.f,0.f}, ar = {0.f,0.f,0.f,0.f}, ah = {0.f,0.f,0.f,0.f};
        const float* w = WT + jb*(32*12);
        #pragma unroll
        for (int k = 0; k < DPDIM; ++k) {
            const float xk = x[k];
            ACC4F(az, xk, *(const float4*)(w));
            ACC4F(ar, xk, *(const float4*)(w + 4));
            ACC4F(ah, xk, *(const float4*)(w + 8));
            w += 12;
        }
        const float4 bz = *(const float4*)(bi + jb*4);
        const float4 br = *(const float4*)(bi + 32 + jb*4);
        const float4 bhi = *(const float4*)(bi + 64 + jb*4);
        const float4 cz = *(const float4*)(bh + jb*4);
        const float4 cr = *(const float4*)(bh + 32 + jb*4);
        *(float4*)(Gp + jb*4)      = make_float4(az.x+bz.x+cz.x, az.y+bz.y+cz.y,
                                                 az.z+bz.z+cz.z, az.w+bz.w+cz.w);
        *(float4*)(Gp + 32 + jb*4) = make_float4(ar.x+br.x+cr.x, ar.y+br.y+cr.y,
                                                 ar.z+br.z+cr.z, ar.w+br.w+cr.w);
        *(float4*)(Gp + 64 + jb*4) = make_float4(ah.x+bhi.x, ah.y+bhi.y,
                                                 ah.z+bhi.z, ah.w+bhi.w);
    }
    nzf[i] = nz ? 1 : 0;
}

// ---------------- path GRU: 8 masked steps, x-gates precomputed ------------
// Accumulators start at ZERO; Gi is added in the epilogue so the divergent
// gather loads have the whole k-loop (~770 cyc) as latency slack.
__global__ __launch_bounds__(64, 1) void path_kernel(
    const float* __restrict__ Gi, const int* __restrict__ nzf,
    float* __restrict__ path_state, const int* __restrict__ link_to_path,
    const float* __restrict__ UpT, const float* __restrict__ bhp, int n_paths)
{
    __shared__ float hbuf[2*DPDIM*64];    // 16 KB, [buf][k][lane]
    int t = threadIdx.x;
    int p = blockIdx.x * 64 + t;
    bool act = p < n_paths;
    int pp = act ? p : (n_paths - 1);
    {
        const float4* row = (const float4*)(path_state + (size_t)pp * DPDIM);
        #pragma unroll
        for (int k4 = 0; k4 < 8; ++k4) {
            float4 v = row[k4];
            hbuf[(4*k4+0)*64 + t] = v.x; hbuf[(4*k4+1)*64 + t] = v.y;
            hbuf[(4*k4+2)*64 + t] = v.z; hbuf[(4*k4+3)*64 + t] = v.w;
        }
    }
    int cur = 0;
    int l = link_to_path[pp*PLEN];        // software-pipelined link index
    #pragma unroll 1
    for (int s = 0; s < PLEN; ++s) {
        int l_next = (s+1 < PLEN) ? link_to_path[pp*PLEN + s + 1] : 0;
        bool nz = act && (nzf[l] != 0);
        const float* G = Gi + (size_t)l * GCOLS;
        const float* hold = hbuf + cur*(DPDIM*64) + t;
        float* hnew = hbuf + (cur^1)*(DPDIM*64) + t;
        #pragma unroll 1
        for (int jb = 0; jb < 8; ++jb) {
            // gather loads issued here, consumed only in the epilogue
            const float4 giz = *(const float4*)(G + jb*4);
            const float4 gir = *(const float4*)(G + 32 + jb*4);
            const float4 gih = *(const float4*)(G + 64 + jb*4);
            float4 az = {0.f,0.f,0.f,0.f}, ar = {0.f,0.f,0.f,0.f}, ah = {0.f,0.f,0.f,0.f};
            const float* w = UpT + jb*(32*12);
            #pragma unroll
            for (int k = 0; k < DPDIM; ++k) {
                float hk = hold[k*64];
                ACC4F(az, hk, *(const float4*)(w));
                ACC4F(ar, hk, *(const float4*)(w + 4));
                ACC4F(ah, hk, *(const float4*)(w + 8));
                w += 12;
            }
            const float4 bhh = *(const float4*)(bhp + 64 + jb*4);   // uniform
#define PWC(C, j) { \
            float zz = fast_sigmoid(az.C + giz.C); \
            float rr = fast_sigmoid(ar.C + gir.C); \
            float cc = fast_tanh(gih.C + rr * (ah.C + bhh.C)); \
            float ho = hold[(jb*4+j)*64]; \
            hnew[(jb*4+j)*64] = nz ? (cc + zz * (ho - cc)) : ho; }
            PWC(x, 0) PWC(y, 1) PWC(z, 2) PWC(w, 3)
#undef PWC
        }
        cur ^= 1;
        l = l_next;
    }
    if (act) {
        const float* hf = hbuf + cur*(DPDIM*64) + t;
        float4* row = (float4*)(path_state + (size_t)p * DPDIM);
        #pragma unroll
        for (int k4 = 0; k4 < 8; ++k4)
            row[k4] = make_float4(hf[(4*k4+0)*64], hf[(4*k4+1)*64],
                                  hf[(4*k4+2)*64], hf[(4*k4+3)*64]);
    }
}

// ---------------- segment sum: path states -> per-link sums ----------------
__global__ __launch_bounds__(256) void seg_sum_kernel(
    const float* __restrict__ path_state, const int* __restrict__ offsets,
    const int* __restrict__ entries, float* __restrict__ path_sum, int n_links)
{
    int t = threadIdx.x;
    int d = t & 31, li = t >> 5;        // 8 links per block, 32 dims each
    int l = blockIdx.x * 8 + li;
    if (l >= n_links) return;
    int beg = offsets[l], end = offsets[l+1];
    float a0 = 0.f, a1 = 0.f, a2 = 0.f, a3 = 0.f;
    int q = beg;
    for (; q + 3 < end; q += 4) {
        int p0 = entries[q], p1 = entries[q+1], p2 = entries[q+2], p3 = entries[q+3];
        a0 += path_state[(size_t)p0 * DPDIM + d];
        a1 += path_state[(size_t)p1 * DPDIM + d];
        a2 += path_state[(size_t)p2 * DPDIM + d];
        a3 += path_state[(size_t)p3 * DPDIM + d];
    }
    for (; q < end; ++q)
        a0 += path_state[(size_t)entries[q] * DPDIM + d];
    path_sum[(size_t)l * DPDIM + d] = (a0 + a1) + (a2 + a3);
}

// ---------------- GRU apply (link update): one step, gates in G ------------
__global__ __launch_bounds__(64, 1) void gru_apply_kernel(
    const float* __restrict__ G, float* __restrict__ state,
    const float* __restrict__ UT, const float* __restrict__ bh, int n)
{
    __shared__ float hbuf[2*DPDIM*64];    // [buf][k][lane]
    int t = threadIdx.x;
    int i = blockIdx.x * 64 + t;
    bool act = i < n;
    int ii = act ? i : (n - 1);
    {
        const float4* row = (const float4*)(state + (size_t)ii * DPDIM);
        #pragma unroll
        for (int k4 = 0; k4 < 8; ++k4) {
            float4 v = row[k4];
            hbuf[(4*k4+0)*64 + t] = v.x; hbuf[(4*k4+1)*64 + t] = v.y;
            hbuf[(4*k4+2)*64 + t] = v.z; hbuf[(4*k4+3)*64 + t] = v.w;
        }
    }
    const float* Gp = G + (size_t)ii * GCOLS;
    const float* hold = hbuf + t;
    float* hnew = hbuf + DPDIM*64 + t;
    #pragma unroll 1
    for (int jb = 0; jb < 8; ++jb) {
        const float4 giz = *(const float4*)(Gp + jb*4);
        const float4 gir = *(const float4*)(Gp + 32 + jb*4);
        const float4 gih = *(const float4*)(Gp + 64 + jb*4);
        float4 az = {0.f,0.f,0.f,0.f}, ar = {0.f,0.f,0.f,0.f}, ah = {0.f,0.f,0.f,0.f};
        const float* w = UT + jb*(32*12);
        #pragma unroll
        for (int k = 0; k < DPDIM; ++k) {
            float hk = hold[k*64];
            ACC4F(az, hk, *(const float4*)(w));
            ACC4F(ar, hk, *(const float4*)(w + 4));
            ACC4F(ah, hk, *(const float4*)(w + 8));
            w += 12;
        }
        const float4 bhh = *(const float4*)(bh + 64 + jb*4);   // uniform
#define PWC(C, j) { \
        float zz = fast_sigmoid(az.C + giz.C); \
        float rr = fast_sigmoid(ar.C + gir.C); \
        float cc = fast_tanh(gih.C + rr * (ah.C + bhh.C)); \
        float ho = hold[(jb*4+j)*64]; \
        hnew[(jb*4+j)*64] = cc + zz * (ho - cc); }
        PWC(x, 0) PWC(y, 1) PWC(z, 2) PWC(w, 3)
#undef PWC
    }
    if (act) {
        const float* hf = hbuf + DPDIM*64 + t;
        float4* row = (float4*)(state + (size_t)i * DPDIM);
        #pragma unroll
        for (int k4 = 0; k4 < 8; ++k4)
            row[k4] = make_float4(hf[(4*k4+0)*64], hf[(4*k4+1)*64],
                                  hf[(4*k4+2)*64], hf[(4*k4+3)*64]);
    }
}

// ---------------- readout: relu(ls@W1+b1) -> relu(@W2+b2) -> @W3+b3 --------
__global__ __launch_bounds__(256) void readout_kernel(
    const float* __restrict__ link_state,
    const float* __restrict__ W1, const float* __restrict__ b1,
    const float* __restrict__ W2, const float* __restrict__ b2,
    const float* __restrict__ W3, const float* __restrict__ b3,
    float* __restrict__ out, int n_links)
{
    __shared__ __align__(16) float s_ls[64*DPDIM];   // 8 KB
    __shared__ float s_m[64*257];                    // 64.25 KB (r1, then r2*w3)
    __shared__ float s_part[256];
    __shared__ float s_w3[RUNITS];
    int t = threadIdx.x;
    int l0 = blockIdx.x * 64;
    int nl = n_links - l0; if (nl > 64) nl = 64;
    for (int i = t; i < nl*DPDIM; i += 256) s_ls[i] = link_state[(size_t)l0*DPDIM + i];
    s_w3[t] = W3[t];
    __syncthreads();
    float w1c[DPDIM];
    #pragma unroll
    for (int k = 0; k < DPDIM; ++k) w1c[k] = W1[k*RUNITS + t];
    float b1t = b1[t];
    for (int i = 0; i < nl; ++i) {
        float a = b1t;
        #pragma unroll
        for (int k = 0; k < DPDIM; ++k) a = fmaf(s_ls[i*DPDIM + k], w1c[k], a);
        s_m[i*257 + t] = fmaxf(a, 0.f);
    }
    __syncthreads();
    float acc[64];
    #pragma unroll
    for (int i = 0; i < 64; ++i) acc[i] = 0.f;
    for (int k = 0; k < RUNITS; ++k) {
        float w = W2[k*RUNITS + t];
        #pragma unroll
        for (int i = 0; i < 64; ++i) acc[i] = fmaf(s_m[i*257 + k], w, acc[i]);
    }
    __syncthreads();
    float b2t = b2[t];
    #pragma unroll
    for (int i = 0; i < 64; ++i)
        s_m[i*257 + t] = fmaxf(acc[i] + b2t, 0.f) * s_w3[t];
    __syncthreads();
    {
        int i = t >> 2, q = t & 3;
        float ssum = 0.f;
        for (int j = q*64; j < q*64 + 64; ++j) ssum += s_m[i*257 + j];
        s_part[t] = ssum;
    }
    __syncthreads();
    if (t < nl)
        out[l0 + t] = b3[0] + s_part[t*4] + s_part[t*4+1] + s_part[t*4+2] + s_part[t*4+3];
}

// ---------------- launch ----------------
extern "C" void kernel_launch(void* const* d_in, const int* in_sizes, int n_in,
                              void* d_out, int out_size, void* d_ws, size_t ws_size,
                              hipStream_t stream)
{
    const float* traffic  = (const float*)d_in[0];
    const float* packets  = (const float*)d_in[1];
    const float* eqlam    = (const float*)d_in[2];
    const float* avgpkt   = (const float*)d_in[3];
    const float* capacity = (const float*)d_in[4];
    const float* queues   = (const float*)d_in[5];
    const int* link_to_path = (const int*)d_in[6];
    const float* Wp  = (const float*)d_in[13];
    const float* Up  = (const float*)d_in[14];
    const float* bip = (const float*)d_in[15];
    const float* bhp = (const float*)d_in[16];
    const float* Wl  = (const float*)d_in[17];
    const float* Ul  = (const float*)d_in[18];
    const float* bil = (const float*)d_in[19];
    const float* bhl = (const float*)d_in[20];
    const float* W1  = (const float*)d_in[21];
    const float* b1  = (const float*)d_in[22];
    const float* W2  = (const float*)d_in[23];
    const float* b2  = (const float*)d_in[24];
    const float* W3  = (const float*)d_in[25];
    const float* b3  = (const float*)d_in[26];
    const int n_paths = in_sizes[0];     // 100000
    const int n_links = in_sizes[4];     // 20000
    const int n_ent   = in_sizes[6];     // 800000

    char* ws = (char*)d_ws;
    size_t off = 0;
    auto salloc = [&](size_t bytes) -> void* {
        void* p = ws + off;
        off += (bytes + 255) & ~size_t(255);
        return p;
    };
    float* path_state = (float*)salloc((size_t)n_paths * DPDIM * 4);
    float* link_state = (float*)salloc((size_t)n_links * DPDIM * 4);
    // Gi (gate_pre -> path_kernel) and path_sum (seg_sum -> gate_pre(link))
    // never overlap in time; alias. Gl is live while path_sum is input -> own buffer.
    float* Gi         = (float*)salloc((size_t)n_links * GCOLS * 4);
    float* path_sum   = Gi;
    float* Gl         = (float*)salloc((size_t)n_links * GCOLS * 4);
    float* UpT   = (float*)salloc((size_t)8 * 32 * 12 * 4);
    float* WpT   = (float*)salloc((size_t)8 * 32 * 12 * 4);
    float* WlT   = (float*)salloc((size_t)8 * 32 * 12 * 4);
    float* UlT   = (float*)salloc((size_t)8 * 32 * 12 * 4);
    int* nzf     = (int*)salloc((size_t)n_links * 4);
    int* counts  = (int*)salloc((size_t)n_links * 4);
    int* offsets = (int*)salloc((size_t)(n_links + 1) * 4);
    int* cursor  = (int*)salloc((size_t)n_links * 4);
    int* entries = (int*)salloc((size_t)n_ent * 4);
    (void)ws_size; (void)n_in; (void)out_size;

    int gmax = ( (n_paths > n_links ? n_paths : n_links) + 255 ) / 256;
    zero_counts_kernel<<<(n_links + 255)/256, 256, 0, stream>>>(counts, n_links);
    init_kernel<<<gmax, 256, 0, stream>>>(traffic, packets, eqlam, avgpkt,
                                          capacity, queues, path_state, link_state,
                                          n_paths, n_links);
    transpose_w_kernel<<<(8*32*12 + 255)/256, 256, 0, stream>>>(Up, UpT);
    transpose_w_kernel<<<(8*32*12 + 255)/256, 256, 0, stream>>>(Wp, WpT);
    transpose_w_kernel<<<(8*32*12 + 255)/256, 256, 0, stream>>>(Wl, WlT);
    transpose_w_kernel<<<(8*32*12 + 255)/256, 256, 0, stream>>>(Ul, UlT);
    hist_kernel<<<(n_ent + 255)/256, 256, 0, stream>>>(link_to_path, counts, n_ent);
    scan_kernel<<<1, 1024, 0, stream>>>(counts, offsets, cursor, n_links);
    fill_kernel<<<(n_ent + 255)/256, 256, 0, stream>>>(link_to_path, cursor, entries, n_ent);

    int gl = (n_links + 63) / 64;
    for (int it = 0; it < T_ITERS; ++it) {
        gate_pre_kernel<<<gl, 64, 0, stream>>>(
            link_state, WpT, bip, bhp, Gi, nzf, n_links);
        path_kernel<<<(n_paths + 63)/64, 64, 0, stream>>>(
            Gi, nzf, path_state, link_to_path, UpT, bhp, n_paths);
        seg_sum_kernel<<<(n_links + 7)/8, 256, 0, stream>>>(
            path_state, offsets, entries, path_sum, n_links);
        gate_pre_kernel<<<gl, 64, 0, stream>>>(
            path_sum, WlT, bil, bhl, Gl, cursor /*dummy*/, n_links);
        gru_apply_kernel<<<gl, 64, 0, stream>>>(
            Gl, link_state, UlT, bhl, n_links);
    }
    readout_kernel<<<(n_links + 63)/64, 256, 0, stream>>>(
        link_state, W1, b1, W2, b2, W3, b3, (float*)d_out, n_links);
}